// Round 8
// baseline (221.844 us; speedup 1.0000x reference)
//
#include <hip/hip_runtime.h>
#include <hip/hip_bf16.h>
#include <math.h>

// NNUE-style sparse feature transform + output head.
// Round 8: revert to the R6-proven block structure (LDS staging, barriers,
// parity split, simple unrolled body) after R7's wave-per-row/__shfl kernel
// failed post-timing validation (unexplained replay-dependent divergence).
// Change vs R6: 256 threads = 4 waves per batch row, entries j == wid (mod 4)
// -> per-wave serial chain 16 -> 8 entries; epilogue combines the 4 waves'
// partials through barrier-fenced LDS. Everything else identical to R6.

constexpr int FT      = 512;
constexpr int FV      = 768;
constexpr int CHUNK   = 64;    // staged segment entries per outer iteration

typedef __attribute__((ext_vector_type(8))) unsigned short ushort8_t;

__device__ inline unsigned short f2bf(float x) {     // RNE f32 -> bf16 bits
    union { float f; unsigned int u; } v; v.f = x;
    unsigned int r = v.u + 0x7FFFu + ((v.u >> 16) & 1u);
    return (unsigned short)(r >> 16);
}
__device__ inline float bf2f(unsigned short s) {     // bf16 bits -> f32
    union { unsigned int u; float f; } v; v.u = ((unsigned int)s) << 16;
    return v.f;
}

// ---- prepass 1: seg_start[b] = lower_bound(batch_ids, b), b in [0, B] ----
__global__ __launch_bounds__(256)
void bounds_kernel(const int* __restrict__ batch_ids, int nnz, int B,
                   int* __restrict__ seg_start)
{
    int b = blockIdx.x * 256 + threadIdx.x;
    if (b > B) return;
    int lo = 0, hi = nnz;
    while (lo < hi) {
        int mid = (lo + hi) >> 1;
        if (batch_ids[mid] < b) lo = mid + 1; else hi = mid;
    }
    seg_start[b] = lo;
}

// ---- prepass 2: W_comb[f][c] = bf16(W_ft[f][c] + W_fft[f%768][c]) ----
__global__ __launch_bounds__(256)
void convert_kernel(const float* __restrict__ W_ft, const float* __restrict__ W_fft,
                    unsigned short* __restrict__ comb, int n8)
{
    int i = blockIdx.x * 256 + threadIdx.x;   // 8-element group index
    if (i >= n8) return;
    const int f    = i >> 6;                  // 64 groups of 8 per 512-col row
    const int gcol = (i & 63) * 8;
    const int base = i * 8;
    const int vrow = (f % FV) * FT + gcol;

    const float4 a0 = *(const float4*)(W_ft  + base);
    const float4 a1 = *(const float4*)(W_ft  + base + 4);
    const float4 b0 = *(const float4*)(W_fft + vrow);
    const float4 b1 = *(const float4*)(W_fft + vrow + 4);

    ushort8_t u;
    u[0] = f2bf(a0.x + b0.x); u[1] = f2bf(a0.y + b0.y);
    u[2] = f2bf(a0.z + b0.z); u[3] = f2bf(a0.w + b0.w);
    u[4] = f2bf(a1.x + b1.x); u[5] = f2bf(a1.y + b1.y);
    u[6] = f2bf(a1.z + b1.z); u[7] = f2bf(a1.w + b1.w);
    *(ushort8_t*)(comb + base) = u;
}

// ---- main kernel: 4 waves per batch row, parity-4 entry split ----
__global__ __launch_bounds__(256)
void nnue4_kernel(const float* __restrict__ values,
                  const unsigned short* __restrict__ Wc,
                  const float* __restrict__ ft_b,
                  const float* __restrict__ fft_b,
                  const float* __restrict__ W_out,
                  const float* __restrict__ out_b,
                  const int*   __restrict__ seg_start,
                  const int*   __restrict__ stm_feat,
                  const int*   __restrict__ nstm_feat,
                  float* __restrict__ out)
{
    const int b    = blockIdx.x;
    const int t    = threadIdx.x;
    const int wid  = t >> 6;       // wave 0..3
    const int lane = t & 63;
    const int col  = lane * 8;     // 8 columns per lane (all 512 per wave)

    const int seg_lo = seg_start[b];
    const int seg_hi = seg_start[b + 1];

    __shared__ int   sh_os[CHUNK];
    __shared__ int   sh_on[CHUNK];
    __shared__ float sh_v [CHUNK];
    __shared__ float sh_part[3][2][FT];   // waves 1..3 partials (stm, nstm)

    float acc_s[8] = {0,0,0,0,0,0,0,0};
    float acc_n[8] = {0,0,0,0,0,0,0,0};

    for (int base = seg_lo; base < seg_hi; base += CHUNK) {
        const int cnt = min(CHUNK, seg_hi - base);
        __syncthreads();
        if (t < cnt) {
            sh_os[t] = stm_feat [base + t] * FT;
            sh_on[t] = nstm_feat[base + t] * FT;
            sh_v [t] = values[base + t];
        }
        __syncthreads();

        // this wave handles entries j == wid (mod 4); simple body (R3 lesson)
        #pragma unroll 4
        for (int j = wid; j < cnt; j += 4) {
            const float v = sh_v[j];
            const ushort8_t a = *(const ushort8_t*)(Wc + sh_os[j] + col);
            const ushort8_t c = *(const ushort8_t*)(Wc + sh_on[j] + col);
            #pragma unroll
            for (int k = 0; k < 8; ++k) {
                acc_s[k] = fmaf(bf2f(a[k]), v, acc_s[k]);
                acc_n[k] = fmaf(bf2f(c[k]), v, acc_n[k]);
            }
        }
    }

    // combine the 4 waves' partials through barrier-fenced LDS
    __syncthreads();
    if (wid > 0) {
        #pragma unroll
        for (int k = 0; k < 8; ++k) {
            sh_part[wid - 1][0][col + k] = acc_s[k];
            sh_part[wid - 1][1][col + k] = acc_n[k];
        }
    }
    __syncthreads();

    if (wid == 0) {
        #pragma unroll
        for (int k = 0; k < 8; ++k) {
            acc_s[k] += sh_part[0][0][col + k] + sh_part[1][0][col + k] + sh_part[2][0][col + k];
            acc_n[k] += sh_part[0][1][col + k] + sh_part[1][1][col + k] + sh_part[2][1][col + k];
        }

        const float4 fb0 = *(const float4*)(ft_b  + col);
        const float4 fb1 = *(const float4*)(ft_b  + col + 4);
        const float4 vb0 = *(const float4*)(fft_b + col);
        const float4 vb1 = *(const float4*)(fft_b + col + 4);
        const float4 ws0 = *(const float4*)(W_out + col);
        const float4 ws1 = *(const float4*)(W_out + col + 4);
        const float4 wn0 = *(const float4*)(W_out + FT + col);
        const float4 wn1 = *(const float4*)(W_out + FT + col + 4);

        const float bias[8] = { fb0.x + vb0.x, fb0.y + vb0.y, fb0.z + vb0.z, fb0.w + vb0.w,
                                fb1.x + vb1.x, fb1.y + vb1.y, fb1.z + vb1.z, fb1.w + vb1.w };
        const float wos[8]  = { ws0.x, ws0.y, ws0.z, ws0.w, ws1.x, ws1.y, ws1.z, ws1.w };
        const float won[8]  = { wn0.x, wn0.y, wn0.z, wn0.w, wn1.x, wn1.y, wn1.z, wn1.w };

        float partial = 0.f;
        #pragma unroll
        for (int k = 0; k < 8; ++k) {
            float hs = fminf(fmaxf(acc_s[k] + bias[k], 0.f), 1.f);
            float hn = fminf(fmaxf(acc_n[k] + bias[k], 0.f), 1.f);
            partial = fmaf(hs, wos[k], partial);
            partial = fmaf(hn, won[k], partial);
        }

        #pragma unroll
        for (int off = 32; off > 0; off >>= 1)
            partial += __shfl_down(partial, off, 64);

        if (lane == 0)
            out[b] = 1.0f / (1.0f + expf(-(partial + out_b[0])));
    }
}

// ---- f32 fallback (Round-2 kernel) if ws too small ----
__global__ __launch_bounds__(128)
void nnue_f32_kernel(const float* __restrict__ values,
                     const float* __restrict__ W_ft,
                     const float* __restrict__ ft_b,
                     const float* __restrict__ W_fft,
                     const float* __restrict__ fft_b,
                     const float* __restrict__ W_out,
                     const float* __restrict__ out_b,
                     const int*   __restrict__ batch_ids,
                     const int*   __restrict__ stm_feat,
                     const int*   __restrict__ nstm_feat,
                     int nnz,
                     float* __restrict__ out)
{
    const int b   = blockIdx.x;
    const int t   = threadIdx.x;
    const int col = t * 4;

    int lo0 = 0, hi0 = nnz;
    while (lo0 < hi0) {
        int mid = (lo0 + hi0) >> 1;
        if (batch_ids[mid] < b) lo0 = mid + 1; else hi0 = mid;
    }
    int lo1 = lo0, hi1 = nnz;
    while (lo1 < hi1) {
        int mid = (lo1 + hi1) >> 1;
        if (batch_ids[mid] < b + 1) lo1 = mid + 1; else hi1 = mid;
    }
    const int seg_lo = lo0, seg_hi = lo1;

    __shared__ int   sh_off_s [128];
    __shared__ int   sh_off_sv[128];
    __shared__ int   sh_off_n [128];
    __shared__ int   sh_off_nv[128];
    __shared__ float sh_v     [128];

    float4 acc_s = make_float4(0.f, 0.f, 0.f, 0.f);
    float4 acc_n = make_float4(0.f, 0.f, 0.f, 0.f);

    for (int base = seg_lo; base < seg_hi; base += 128) {
        const int cnt = min(128, seg_hi - base);
        __syncthreads();
        if (t < cnt) {
            int fs = stm_feat[base + t];
            int fn = nstm_feat[base + t];
            sh_off_s [t] = fs * FT;
            sh_off_sv[t] = (fs % FV) * FT;
            sh_off_n [t] = fn * FT;
            sh_off_nv[t] = (fn % FV) * FT;
            sh_v     [t] = values[base + t];
        }
        __syncthreads();

        #pragma unroll 2
        for (int j = 0; j < cnt; ++j) {
            const float v = sh_v[j];
            const float4 a  = *(const float4*)(W_ft  + sh_off_s [j] + col);
            const float4 av = *(const float4*)(W_fft + sh_off_sv[j] + col);
            const float4 c  = *(const float4*)(W_ft  + sh_off_n [j] + col);
            const float4 cv = *(const float4*)(W_fft + sh_off_nv[j] + col);
            acc_s.x = fmaf(a.x + av.x, v, acc_s.x);
            acc_s.y = fmaf(a.y + av.y, v, acc_s.y);
            acc_s.z = fmaf(a.z + av.z, v, acc_s.z);
            acc_s.w = fmaf(a.w + av.w, v, acc_s.w);
            acc_n.x = fmaf(c.x + cv.x, v, acc_n.x);
            acc_n.y = fmaf(c.y + cv.y, v, acc_n.y);
            acc_n.z = fmaf(c.z + cv.z, v, acc_n.z);
            acc_n.w = fmaf(c.w + cv.w, v, acc_n.w);
        }
    }

    const float4 fb  = *(const float4*)(ft_b  + col);
    const float4 vb  = *(const float4*)(fft_b + col);
    const float4 wos = *(const float4*)(W_out + col);
    const float4 won = *(const float4*)(W_out + FT + col);

    float partial = 0.f;
    {
        float h;
        h = fminf(fmaxf(acc_s.x + fb.x + vb.x, 0.f), 1.f); partial = fmaf(h, wos.x, partial);
        h = fminf(fmaxf(acc_s.y + fb.y + vb.y, 0.f), 1.f); partial = fmaf(h, wos.y, partial);
        h = fminf(fmaxf(acc_s.z + fb.z + vb.z, 0.f), 1.f); partial = fmaf(h, wos.z, partial);
        h = fminf(fmaxf(acc_s.w + fb.w + vb.w, 0.f), 1.f); partial = fmaf(h, wos.w, partial);
        h = fminf(fmaxf(acc_n.x + fb.x + vb.x, 0.f), 1.f); partial = fmaf(h, won.x, partial);
        h = fminf(fmaxf(acc_n.y + fb.y + vb.y, 0.f), 1.f); partial = fmaf(h, won.y, partial);
        h = fminf(fmaxf(acc_n.z + fb.z + vb.z, 0.f), 1.f); partial = fmaf(h, won.z, partial);
        h = fminf(fmaxf(acc_n.w + fb.w + vb.w, 0.f), 1.f); partial = fmaf(h, won.w, partial);
    }

    #pragma unroll
    for (int off = 32; off > 0; off >>= 1)
        partial += __shfl_down(partial, off, 64);

    __shared__ float wave_sum[2];
    if ((t & 63) == 0) wave_sum[t >> 6] = partial;
    __syncthreads();
    if (t == 0) {
        float s = wave_sum[0] + wave_sum[1] + out_b[0];
        out[b] = 1.0f / (1.0f + expf(-s));
    }
}

extern "C" void kernel_launch(void* const* d_in, const int* in_sizes, int n_in,
                              void* d_out, int out_size, void* d_ws, size_t ws_size,
                              hipStream_t stream) {
    const float* values    = (const float*)d_in[0];
    const float* W_ft      = (const float*)d_in[1];
    const float* ft_b      = (const float*)d_in[2];
    const float* W_fft     = (const float*)d_in[3];
    const float* fft_b     = (const float*)d_in[4];
    const float* W_out     = (const float*)d_in[5];
    const float* out_b     = (const float*)d_in[6];
    const int*   batch_ids = (const int*)d_in[7];
    const int*   stm_feat  = (const int*)d_in[8];
    const int*   nstm_feat = (const int*)d_in[9];

    const int nnz  = in_sizes[0];
    const int B    = out_size;
    const int n_ft = in_sizes[1];   // F_FULL*FT elements

    // workspace layout: [comb table: n_ft ushort][seg_start: B+1 int]
    const size_t comb_bytes = (size_t)n_ft * sizeof(unsigned short);
    const size_t need = comb_bytes + (size_t)(B + 1) * sizeof(int);

    if (ws_size >= need) {
        unsigned short* comb = (unsigned short*)d_ws;
        int* seg_start = (int*)((char*)d_ws + comb_bytes);

        const int n8    = n_ft / 8;
        const int cgrid = (n8 + 255) / 256;
        const int bgrid = (B + 1 + 255) / 256;

        bounds_kernel<<<bgrid, 256, 0, stream>>>(batch_ids, nnz, B, seg_start);
        convert_kernel<<<cgrid, 256, 0, stream>>>(W_ft, W_fft, comb, n8);
        nnue4_kernel<<<B, 256, 0, stream>>>(
            values, comb, ft_b, fft_b, W_out, out_b,
            seg_start, stm_feat, nstm_feat, (float*)d_out);
    } else {
        nnue_f32_kernel<<<B, 128, 0, stream>>>(
            values, W_ft, ft_b, W_fft, fft_b, W_out, out_b,
            batch_ids, stm_feat, nstm_feat, nnz, (float*)d_out);
    }
}

// Round 9
// 215.568 us; speedup vs baseline: 1.0291x; 1.0291x over previous
//
#include <hip/hip_runtime.h>
#include <hip/hip_bf16.h>
#include <math.h>

// NNUE-style sparse feature transform + output head.
// Round 9: R6's proven 2-wave block structure, but each block processes 4
// consecutive batch rows sequentially (grid 2048 instead of 8192) — R8 showed
// per-wave chain length is not the limiter; 8192 short blocks are
// dispatch/ramp-limited (occ 37% despite resources for ~16 blocks/CU).
// Also fuses bounds_kernel into the convert launch (trailing blocks) to
// remove one serialized launch. Inner loop body identical to R6.

constexpr int FT      = 512;
constexpr int FV      = 768;
constexpr int CHUNK   = 128;
constexpr int ROWS    = 4;     // batch rows per block (sequential)

typedef __attribute__((ext_vector_type(8))) unsigned short ushort8_t;

__device__ inline unsigned short f2bf(float x) {     // RNE f32 -> bf16 bits
    union { float f; unsigned int u; } v; v.f = x;
    unsigned int r = v.u + 0x7FFFu + ((v.u >> 16) & 1u);
    return (unsigned short)(r >> 16);
}
__device__ inline float bf2f(unsigned short s) {     // bf16 bits -> f32
    union { unsigned int u; float f; } v; v.u = ((unsigned int)s) << 16;
    return v.f;
}

// ---- fused prepass: blocks [0,cgrid) build comb table; trailing blocks
//      compute seg_start[b] = lower_bound(batch_ids, b) ----
__global__ __launch_bounds__(256)
void prepass_kernel(const float* __restrict__ W_ft, const float* __restrict__ W_fft,
                    unsigned short* __restrict__ comb, int n8, int cgrid,
                    const int* __restrict__ batch_ids, int nnz, int B,
                    int* __restrict__ seg_start)
{
    if (blockIdx.x < (unsigned)cgrid) {
        int i = blockIdx.x * 256 + threadIdx.x;   // 8-element group index
        if (i >= n8) return;
        const int f    = i >> 6;                  // 64 groups of 8 per row
        const int base = i * 8;
        const int gcol = (i & 63) * 8;
        const int vrow = (f % FV) * FT + gcol;

        const float4 a0 = *(const float4*)(W_ft  + base);
        const float4 a1 = *(const float4*)(W_ft  + base + 4);
        const float4 b0 = *(const float4*)(W_fft + vrow);
        const float4 b1 = *(const float4*)(W_fft + vrow + 4);

        ushort8_t u;
        u[0] = f2bf(a0.x + b0.x); u[1] = f2bf(a0.y + b0.y);
        u[2] = f2bf(a0.z + b0.z); u[3] = f2bf(a0.w + b0.w);
        u[4] = f2bf(a1.x + b1.x); u[5] = f2bf(a1.y + b1.y);
        u[6] = f2bf(a1.z + b1.z); u[7] = f2bf(a1.w + b1.w);
        *(ushort8_t*)(comb + base) = u;
    } else {
        int b = (blockIdx.x - cgrid) * 256 + threadIdx.x;
        if (b > B) return;
        int lo = 0, hi = nnz;
        while (lo < hi) {
            int mid = (lo + hi) >> 1;
            if (batch_ids[mid] < b) lo = mid + 1; else hi = mid;
        }
        seg_start[b] = lo;
    }
}

// ---- main kernel: 2 waves, 4 sequential batch rows per block ----
__global__ __launch_bounds__(128)
void nnue_kernel(const float* __restrict__ values,
                 const unsigned short* __restrict__ Wc,
                 const float* __restrict__ ft_b,
                 const float* __restrict__ fft_b,
                 const float* __restrict__ W_out,
                 const float* __restrict__ out_b,
                 const int*   __restrict__ seg_start,
                 const int*   __restrict__ stm_feat,
                 const int*   __restrict__ nstm_feat,
                 float* __restrict__ out)
{
    const int t    = threadIdx.x;
    const int w    = t >> 6;       // wave 0 / 1
    const int lane = t & 63;
    const int col  = lane * 8;     // 8 columns per lane

    __shared__ int   sh_os[CHUNK];
    __shared__ int   sh_on[CHUNK];
    __shared__ float sh_v [CHUNK];
    __shared__ float sh_part[2][FT];   // wave-1 partials (stm, nstm)

    for (int r = 0; r < ROWS; ++r) {
        const int b      = blockIdx.x * ROWS + r;
        const int seg_lo = seg_start[b];
        const int seg_hi = seg_start[b + 1];

        float acc_s[8] = {0,0,0,0,0,0,0,0};
        float acc_n[8] = {0,0,0,0,0,0,0,0};

        for (int base = seg_lo; base < seg_hi; base += CHUNK) {
            const int cnt = min(CHUNK, seg_hi - base);
            __syncthreads();
            if (t < cnt) {
                sh_os[t] = stm_feat [base + t] * FT;
                sh_on[t] = nstm_feat[base + t] * FT;
                sh_v [t] = values[base + t];
            }
            __syncthreads();

            // this wave handles entries j == w (mod 2); simple body (R3 lesson)
            #pragma unroll 4
            for (int j = w; j < cnt; j += 2) {
                const float v = sh_v[j];
                const ushort8_t a = *(const ushort8_t*)(Wc + sh_os[j] + col);
                const ushort8_t c = *(const ushort8_t*)(Wc + sh_on[j] + col);
                #pragma unroll
                for (int k = 0; k < 8; ++k) {
                    acc_s[k] = fmaf(bf2f(a[k]), v, acc_s[k]);
                    acc_n[k] = fmaf(bf2f(c[k]), v, acc_n[k]);
                }
            }
        }

        // combine the two waves' partials through barrier-fenced LDS
        __syncthreads();
        if (w == 1) {
            #pragma unroll
            for (int k = 0; k < 8; ++k) {
                sh_part[0][col + k] = acc_s[k];
                sh_part[1][col + k] = acc_n[k];
            }
        }
        __syncthreads();

        if (w == 0) {
            #pragma unroll
            for (int k = 0; k < 8; ++k) {
                acc_s[k] += sh_part[0][col + k];
                acc_n[k] += sh_part[1][col + k];
            }

            const float4 fb0 = *(const float4*)(ft_b  + col);
            const float4 fb1 = *(const float4*)(ft_b  + col + 4);
            const float4 vb0 = *(const float4*)(fft_b + col);
            const float4 vb1 = *(const float4*)(fft_b + col + 4);
            const float4 ws0 = *(const float4*)(W_out + col);
            const float4 ws1 = *(const float4*)(W_out + col + 4);
            const float4 wn0 = *(const float4*)(W_out + FT + col);
            const float4 wn1 = *(const float4*)(W_out + FT + col + 4);

            const float bias[8] = { fb0.x + vb0.x, fb0.y + vb0.y, fb0.z + vb0.z, fb0.w + vb0.w,
                                    fb1.x + vb1.x, fb1.y + vb1.y, fb1.z + vb1.z, fb1.w + vb1.w };
            const float wos[8]  = { ws0.x, ws0.y, ws0.z, ws0.w, ws1.x, ws1.y, ws1.z, ws1.w };
            const float won[8]  = { wn0.x, wn0.y, wn0.z, wn0.w, wn1.x, wn1.y, wn1.z, wn1.w };

            float partial = 0.f;
            #pragma unroll
            for (int k = 0; k < 8; ++k) {
                float hs = fminf(fmaxf(acc_s[k] + bias[k], 0.f), 1.f);
                float hn = fminf(fmaxf(acc_n[k] + bias[k], 0.f), 1.f);
                partial = fmaf(hs, wos[k], partial);
                partial = fmaf(hn, won[k], partial);
            }

            #pragma unroll
            for (int off = 32; off > 0; off >>= 1)
                partial += __shfl_down(partial, off, 64);

            if (lane == 0)
                out[b] = 1.0f / (1.0f + expf(-(partial + out_b[0])));
        }
    }
}

// ---- f32 fallback (Round-2 kernel) if ws too small ----
__global__ __launch_bounds__(128)
void nnue_f32_kernel(const float* __restrict__ values,
                     const float* __restrict__ W_ft,
                     const float* __restrict__ ft_b,
                     const float* __restrict__ W_fft,
                     const float* __restrict__ fft_b,
                     const float* __restrict__ W_out,
                     const float* __restrict__ out_b,
                     const int*   __restrict__ batch_ids,
                     const int*   __restrict__ stm_feat,
                     const int*   __restrict__ nstm_feat,
                     int nnz,
                     float* __restrict__ out)
{
    const int b   = blockIdx.x;
    const int t   = threadIdx.x;
    const int col = t * 4;

    int lo0 = 0, hi0 = nnz;
    while (lo0 < hi0) {
        int mid = (lo0 + hi0) >> 1;
        if (batch_ids[mid] < b) lo0 = mid + 1; else hi0 = mid;
    }
    int lo1 = lo0, hi1 = nnz;
    while (lo1 < hi1) {
        int mid = (lo1 + hi1) >> 1;
        if (batch_ids[mid] < b + 1) lo1 = mid + 1; else hi1 = mid;
    }
    const int seg_lo = lo0, seg_hi = lo1;

    __shared__ int   sh_off_s [128];
    __shared__ int   sh_off_sv[128];
    __shared__ int   sh_off_n [128];
    __shared__ int   sh_off_nv[128];
    __shared__ float sh_v     [128];

    float4 acc_s = make_float4(0.f, 0.f, 0.f, 0.f);
    float4 acc_n = make_float4(0.f, 0.f, 0.f, 0.f);

    for (int base = seg_lo; base < seg_hi; base += 128) {
        const int cnt = min(128, seg_hi - base);
        __syncthreads();
        if (t < cnt) {
            int fs = stm_feat[base + t];
            int fn = nstm_feat[base + t];
            sh_off_s [t] = fs * FT;
            sh_off_sv[t] = (fs % FV) * FT;
            sh_off_n [t] = fn * FT;
            sh_off_nv[t] = (fn % FV) * FT;
            sh_v     [t] = values[base + t];
        }
        __syncthreads();

        #pragma unroll 2
        for (int j = 0; j < cnt; ++j) {
            const float v = sh_v[j];
            const float4 a  = *(const float4*)(W_ft  + sh_off_s [j] + col);
            const float4 av = *(const float4*)(W_fft + sh_off_sv[j] + col);
            const float4 c  = *(const float4*)(W_ft  + sh_off_n [j] + col);
            const float4 cv = *(const float4*)(W_fft + sh_off_nv[j] + col);
            acc_s.x = fmaf(a.x + av.x, v, acc_s.x);
            acc_s.y = fmaf(a.y + av.y, v, acc_s.y);
            acc_s.z = fmaf(a.z + av.z, v, acc_s.z);
            acc_s.w = fmaf(a.w + av.w, v, acc_s.w);
            acc_n.x = fmaf(c.x + cv.x, v, acc_n.x);
            acc_n.y = fmaf(c.y + cv.y, v, acc_n.y);
            acc_n.z = fmaf(c.z + cv.z, v, acc_n.z);
            acc_n.w = fmaf(c.w + cv.w, v, acc_n.w);
        }
    }

    const float4 fb  = *(const float4*)(ft_b  + col);
    const float4 vb  = *(const float4*)(fft_b + col);
    const float4 wos = *(const float4*)(W_out + col);
    const float4 won = *(const float4*)(W_out + FT + col);

    float partial = 0.f;
    {
        float h;
        h = fminf(fmaxf(acc_s.x + fb.x + vb.x, 0.f), 1.f); partial = fmaf(h, wos.x, partial);
        h = fminf(fmaxf(acc_s.y + fb.y + vb.y, 0.f), 1.f); partial = fmaf(h, wos.y, partial);
        h = fminf(fmaxf(acc_s.z + fb.z + vb.z, 0.f), 1.f); partial = fmaf(h, wos.z, partial);
        h = fminf(fmaxf(acc_s.w + fb.w + vb.w, 0.f), 1.f); partial = fmaf(h, wos.w, partial);
        h = fminf(fmaxf(acc_n.x + fb.x + vb.x, 0.f), 1.f); partial = fmaf(h, won.x, partial);
        h = fminf(fmaxf(acc_n.y + fb.y + vb.y, 0.f), 1.f); partial = fmaf(h, won.y, partial);
        h = fminf(fmaxf(acc_n.z + fb.z + vb.z, 0.f), 1.f); partial = fmaf(h, won.z, partial);
        h = fminf(fmaxf(acc_n.w + fb.w + vb.w, 0.f), 1.f); partial = fmaf(h, won.w, partial);
    }

    #pragma unroll
    for (int off = 32; off > 0; off >>= 1)
        partial += __shfl_down(partial, off, 64);

    __shared__ float wave_sum[2];
    if ((t & 63) == 0) wave_sum[t >> 6] = partial;
    __syncthreads();
    if (t == 0) {
        float s = wave_sum[0] + wave_sum[1] + out_b[0];
        out[b] = 1.0f / (1.0f + expf(-s));
    }
}

extern "C" void kernel_launch(void* const* d_in, const int* in_sizes, int n_in,
                              void* d_out, int out_size, void* d_ws, size_t ws_size,
                              hipStream_t stream) {
    const float* values    = (const float*)d_in[0];
    const float* W_ft      = (const float*)d_in[1];
    const float* ft_b      = (const float*)d_in[2];
    const float* W_fft     = (const float*)d_in[3];
    const float* fft_b     = (const float*)d_in[4];
    const float* W_out     = (const float*)d_in[5];
    const float* out_b     = (const float*)d_in[6];
    const int*   batch_ids = (const int*)d_in[7];
    const int*   stm_feat  = (const int*)d_in[8];
    const int*   nstm_feat = (const int*)d_in[9];

    const int nnz  = in_sizes[0];
    const int B    = out_size;
    const int n_ft = in_sizes[1];   // F_FULL*FT elements

    // workspace layout: [comb table: n_ft ushort][seg_start: B+1 int]
    const size_t comb_bytes = (size_t)n_ft * sizeof(unsigned short);
    const size_t need = comb_bytes + (size_t)(B + 1) * sizeof(int);

    if (ws_size >= need && (B % ROWS) == 0) {
        unsigned short* comb = (unsigned short*)d_ws;
        int* seg_start = (int*)((char*)d_ws + comb_bytes);

        const int n8    = n_ft / 8;
        const int cgrid = (n8 + 255) / 256;
        const int bgrid = (B + 1 + 255) / 256;

        prepass_kernel<<<cgrid + bgrid, 256, 0, stream>>>(
            W_ft, W_fft, comb, n8, cgrid, batch_ids, nnz, B, seg_start);
        nnue_kernel<<<B / ROWS, 128, 0, stream>>>(
            values, comb, ft_b, fft_b, W_out, out_b,
            seg_start, stm_feat, nstm_feat, (float*)d_out);
    } else {
        nnue_f32_kernel<<<B, 128, 0, stream>>>(
            values, W_ft, ft_b, W_fft, fft_b, W_out, out_b,
            batch_ids, stm_feat, nstm_feat, nnz, (float*)d_out);
    }
}